// Round 5
// baseline (55.614 us; speedup 1.0000x reference)
//
#include <hip/hip_runtime.h>
#include <hip/hip_bf16.h>
#include <stdint.h>

#define NB   16
#define CIN  2048
#define OUTC 256
#define HW   1024
#define BJ   32
#define BK   64
#define NJT  (HW / BJ)          // 32 j-tiles
#define KSTEPS (CIN / BK)       // 32 steps of 64 k

typedef __attribute__((ext_vector_type(8))) short bf16x8;
typedef __attribute__((ext_vector_type(4))) float f32x4;
typedef __attribute__((ext_vector_type(4))) unsigned int u32x4;

__device__ __forceinline__ unsigned int f2bf(float f) {
    union { float f; unsigned int u; } a; a.f = f;
    return (a.u + 0x7FFFu + ((a.u >> 16) & 1u)) >> 16;  // RNE
}

// Raw barrier: drains LDS ops only; global prefetch loads stay in flight.
__device__ __forceinline__ void block_sync_lds() {
    asm volatile("s_waitcnt lgkmcnt(0)" ::: "memory");
    __builtin_amdgcn_s_barrier();
    asm volatile("" ::: "memory");
}

// ---- kernel 1: W fp32 -> bf16 A-fragments in MFMA lane order.
//      Afrag[ks32][ot][lane][8 bf16]: lane l of fragment (ks32, ot) holds
//      A[row = ot*16 + (l&15)][k = ks32*32 + (l>>4)*8 + i]  (m89 layout).
__global__ void wprep_kernel(const float* __restrict__ W, unsigned short* __restrict__ Afrag) {
    int g  = blockIdx.x * blockDim.x + threadIdx.x;   // 65536
    int o  = g >> 8;           // 0..255
    int kc = g & 255;          // 8-k chunk within row
    const float4* p = reinterpret_cast<const float4*>(W + o * CIN + kc * 8);
    float4 v0 = p[0], v1 = p[1];
    u32x4 pk;
    pk.x = f2bf(v0.x) | (f2bf(v0.y) << 16);
    pk.y = f2bf(v0.z) | (f2bf(v0.w) << 16);
    pk.z = f2bf(v1.x) | (f2bf(v1.y) << 16);
    pk.w = f2bf(v1.z) | (f2bf(v1.w) << 16);
    int ks32 = kc >> 2, g8 = kc & 3;
    int lane = g8 * 16 + (o & 15), ot = o >> 4;
    *reinterpret_cast<u32x4*>(Afrag + (((size_t)ks32 * 16 + ot) * 64 + lane) * 8) = pk;
}

// ---- kernel 2: per-batch GEMM. 4 waves x 64 A-rows (A direct from L2),
//      BJ=32 -> grid 512 = 2 independent barrier domains per CU.
__global__ __launch_bounds__(256, 2) void gemm_stats_kernel(
    const float* __restrict__ x,             // [16][2048][1024]
    const unsigned short* __restrict__ Afrag,
    float* __restrict__ s1_part,             // [NJT][NB][OUTC]
    float* __restrict__ s2_part)             // [512][OUTC]
{
    __shared__ __align__(16) unsigned short B0[2048], B1[2048]; // 4 KB each (32j x 64k)

    const int tid  = threadIdx.x;
    const int lane = tid & 63;
    const int wave = tid >> 6;     // 0..3, wave's o-rows = [64w, 64w+64)
    const int blk  = blockIdx.x;   // 0..511
    const int n    = blk >> 5;
    const int jt   = blk & 31;
    const int j0   = jt * BJ;

    const float* xn = x + (size_t)n * CIN * HW;

    // B staging: thread (bj = tid&31, kh = tid>>5 in 0..7) loads 8 floats
    // (k = kh*8+i) -> one swizzled ds_write_b128.
    const int bj = tid & 31;
    const int kh = tid >> 5;
    const float* Bgp = xn + (size_t)(kh * 8) * HW + j0 + bj;
    const int offB = (kh >> 2) * 1024 + (bj >> 4) * 512 + (bj & 15) * 32
                   + ((kh & 3) ^ (bj & 3)) * 8;

    // fragment read offsets: each (khalf, ni) B fragment is a contiguous
    // 1 KB block read across the wave (conflict-free).
    const int rA = lane & 15;
    const int gX = (lane >> 4) ^ (rA & 3);
    const int roffB = rA * 32 + gX * 8;            // + khalf*1024 + ni*512

    // A fragment source: wave-uniform frag base + lane*16B
    const unsigned short* Ab = Afrag + (size_t)lane * 8;

#define LDA(ks, R) { _Pragma("unroll") \
    for (int h = 0; h < 2; ++h) _Pragma("unroll") for (int mi = 0; mi < 4; ++mi) \
        R[h * 4 + mi] = *(const u32x4*)(Ab + ((((ks) * 2 + h) * 16 + wave * 4 + mi) * 64) * 8); }
#define LDB(ks, F) { const float* p = Bgp + (size_t)(ks) * BK * HW; \
    _Pragma("unroll") for (int i = 0; i < 8; ++i) F[i] = p[(size_t)i * HW]; }
#define WRITEB(Bb, F) { u32x4 pk; \
    pk.x = f2bf(F[0]) | (f2bf(F[1]) << 16); pk.y = f2bf(F[2]) | (f2bf(F[3]) << 16); \
    pk.z = f2bf(F[4]) | (f2bf(F[5]) << 16); pk.w = f2bf(F[6]) | (f2bf(F[7]) << 16); \
    *(u32x4*)&Bb[offB] = pk; }
#define COMPUTE(Bb, R) { _Pragma("unroll") \
    for (int h = 0; h < 2; ++h) _Pragma("unroll") for (int ni = 0; ni < 2; ++ni) { \
        bf16x8 bf = *(const bf16x8*)&Bb[h * 1024 + ni * 512 + roffB]; \
        _Pragma("unroll") \
        for (int mi = 0; mi < 4; ++mi) { \
            bf16x8 af = *(const bf16x8*)&R[h * 4 + mi]; \
            acc[mi][ni] = __builtin_amdgcn_mfma_f32_16x16x32_bf16(af, bf, acc[mi][ni], 0, 0, 0); \
    } } }

    f32x4 acc[4][2] = {};
    u32x4 Ra[8];
    float Bs0[8], Bs1[8];

    // prologue
    LDA(0, Ra);
    LDB(0, Bs0); LDB(1, Bs1);
    WRITEB(B0, Bs0);
    LDB(2, Bs0);
    block_sync_lds();

    #pragma unroll 1
    for (int ks = 0; ks < KSTEPS; ks += 2) {
        // ---- step ks (even): compute buf0
        COMPUTE(B0, Ra);
        LDA(ks + 1, Ra);                       // A for step ks+1
        WRITEB(B1, Bs1);                       // stage data ks+1
        {
            int kb = (ks + 3 < KSTEPS) ? ks + 3 : KSTEPS - 1;
            LDB(kb, Bs1);
        }
        block_sync_lds();
        // ---- step ks+1 (odd): compute buf1
        COMPUTE(B1, Ra);
        {
            int ka = (ks + 2 < KSTEPS) ? ks + 2 : KSTEPS - 1;
            LDA(ka, Ra);                       // A for step ks+2
        }
        if (ks + 2 < KSTEPS) {
            WRITEB(B0, Bs0);                   // stage data ks+2
            int kb = (ks + 4 < KSTEPS) ? ks + 4 : KSTEPS - 1;
            LDB(kb, Bs0);
            block_sync_lds();
        }
    }

    // ---- epilogue: per-channel sum / sum-of-squares over this block's 32 j ----
    // C/D layout: col(j) = lane&15, row = (lane>>4)*4 + r  [m89]
    float rs[4][4], rq[4][4];
    #pragma unroll
    for (int mi = 0; mi < 4; ++mi) {
        #pragma unroll
        for (int r = 0; r < 4; ++r) {
            float v0 = acc[mi][0][r], v1 = acc[mi][1][r];
            rs[mi][r] = v0 + v1;
            rq[mi][r] = v0 * v0 + v1 * v1;
        }
    }
    #pragma unroll
    for (int m = 1; m < 16; m <<= 1) {
        #pragma unroll
        for (int mi = 0; mi < 4; ++mi) {
            #pragma unroll
            for (int r = 0; r < 4; ++r) {
                rs[mi][r] += __shfl_xor(rs[mi][r], m, 64);
                rq[mi][r] += __shfl_xor(rq[mi][r], m, 64);
            }
        }
    }
    if (rA == 0) {
        const int gK = lane >> 4;
        #pragma unroll
        for (int mi = 0; mi < 4; ++mi) {
            #pragma unroll
            for (int r = 0; r < 4; ++r) {
                int o = wave * 64 + mi * 16 + gK * 4 + r;
                s1_part[(jt * NB + n) * OUTC + o] = rs[mi][r];
                s2_part[blk * OUTC + o]           = rq[mi][r];
            }
        }
    }
#undef LDA
#undef LDB
#undef WRITEB
#undef COMPUTE
}

// ---- kernel 3 (fused finalize+broadcast): block = (n, 16 channels).
__global__ __launch_bounds__(256) void finalize_bcast_kernel(
    const float* __restrict__ s1_part,   // [NJT][NB][OUTC]
    const float* __restrict__ s2_part,   // [512][OUTC]
    const float* __restrict__ gamma,
    const float* __restrict__ beta,
    float* __restrict__ out)             // [NB][OUTC][1024]
{
    const int tid   = threadIdx.x;
    const int slice = tid & 15;
    const int o_l   = tid >> 4;
    const int n0    = blockIdx.x >> 4;
    const int o     = (blockIdx.x & 15) * 16 + o_l;

    float S1 = 0.f, S2 = 0.f;
    #pragma unroll
    for (int q = 0; q < 32; ++q) {
        int p = slice * 32 + q;          // covers all 512 partials
        S1 += s1_part[p * OUTC + o];
        S2 += s2_part[p * OUTC + o];
    }
    // this block's n: sum over jt of s1_part[jt][n0][o]; jt = slice*2, slice*2+1
    float s1n = s1_part[(slice * 2 * NB + n0) * OUTC + o]
              + s1_part[((slice * 2 + 1) * NB + n0) * OUTC + o];
    #pragma unroll
    for (int m = 1; m < 16; m <<= 1) {
        S1  += __shfl_xor(S1, m, 64);
        S2  += __shfl_xor(S2, m, 64);
        s1n += __shfl_xor(s1n, m, 64);
    }
    float mean = S1 * (1.f / 16384.f);
    float var  = S2 * (1.f / 16384.f) - mean * mean;   // biased var (matches ref)
    float inv  = rsqrtf(var + 1e-5f);
    float v = gamma[o] * (s1n * (1.f / 1024.f) - mean) * inv + beta[o];

    float4 vv = make_float4(v, v, v, v);
    float4* dst = reinterpret_cast<float4*>(out + ((size_t)(n0 * OUTC + o)) * HW);
    #pragma unroll
    for (int it = 0; it < 16; ++it)
        dst[it * 16 + slice] = vv;
}

extern "C" void kernel_launch(void* const* d_in, const int* in_sizes, int n_in,
                              void* d_out, int out_size, void* d_ws, size_t ws_size,
                              hipStream_t stream) {
    const float* x     = (const float*)d_in[0];
    const float* W     = (const float*)d_in[1];
    const float* gamma = (const float*)d_in[2];
    const float* beta  = (const float*)d_in[3];
    float* out = (float*)d_out;

    char* ws = (char*)d_ws;
    unsigned short* Afrag = (unsigned short*)ws;                 // 1 MiB
    float* s1_part = (float*)(ws + (1 << 20));                   // 512 KB
    float* s2_part = (float*)(ws + (1 << 20) + (512 << 10));     // 512 KB

    hipLaunchKernelGGL(wprep_kernel, dim3(256), dim3(256), 0, stream, W, Afrag);
    hipLaunchKernelGGL(gemm_stats_kernel, dim3(NB * NJT), dim3(256), 0, stream,
                       x, Afrag, s1_part, s2_part);
    hipLaunchKernelGGL(finalize_bcast_kernel, dim3(NB * (OUTC / 16)), dim3(256), 0, stream,
                       s1_part, s2_part, gamma, beta, out);
}

// Round 6
// 48.414 us; speedup vs baseline: 1.1487x; 1.1487x over previous
//
#include <hip/hip_runtime.h>
#include <hip/hip_bf16.h>
#include <stdint.h>

#define NB   16
#define CIN  2048
#define OUTC 256
#define HW   1024
#define BJ   64
#define BK   64
#define NJT  (HW / BJ)          // 16 j-tiles
#define KSTEPS (CIN / BK)       // 32 steps of 64 k

typedef __attribute__((ext_vector_type(8))) short bf16x8;
typedef __attribute__((ext_vector_type(4))) float f32x4;
typedef __attribute__((ext_vector_type(4))) unsigned int u32x4;

__device__ __forceinline__ unsigned int f2bf(float f) {
    union { float f; unsigned int u; } a; a.f = f;
    return (a.u + 0x7FFFu + ((a.u >> 16) & 1u)) >> 16;  // RNE
}

// Raw barrier: drains LDS ops only; global prefetch loads stay in flight.
__device__ __forceinline__ void block_sync_lds() {
    asm volatile("s_waitcnt lgkmcnt(0)" ::: "memory");
    __builtin_amdgcn_s_barrier();
    asm volatile("" ::: "memory");
}

// ---- kernel 1: W fp32 -> bf16 A-fragments in MFMA lane order.
//      Afrag[ks32][ot][lane][8 bf16]: lane l of fragment (ks32, ot) holds
//      A[row = ot*16 + (l&15)][k = ks32*32 + (l>>4)*8 + i]  (m89 layout).
__global__ void wprep_kernel(const float* __restrict__ W, unsigned short* __restrict__ Afrag) {
    int g  = blockIdx.x * blockDim.x + threadIdx.x;   // 65536
    int o  = g >> 8;           // 0..255
    int kc = g & 255;          // 8-k chunk within row
    const float4* p = reinterpret_cast<const float4*>(W + o * CIN + kc * 8);
    float4 v0 = p[0], v1 = p[1];
    u32x4 pk;
    pk.x = f2bf(v0.x) | (f2bf(v0.y) << 16);
    pk.y = f2bf(v0.z) | (f2bf(v0.w) << 16);
    pk.z = f2bf(v1.x) | (f2bf(v1.y) << 16);
    pk.w = f2bf(v1.z) | (f2bf(v1.w) << 16);
    int ks32 = kc >> 2, g8 = kc & 3;
    int lane = g8 * 16 + (o & 15), ot = o >> 4;
    *reinterpret_cast<u32x4*>(Afrag + (((size_t)ks32 * 16 + ot) * 64 + lane) * 8) = pk;
}

// ---- kernel 2: per-batch GEMM, B-only LDS (swizzled), A direct from L2
//      with DOUBLE-BUFFERED A register sets (1-step refill lead).
__global__ __launch_bounds__(512, 2) void gemm_stats_kernel(
    const float* __restrict__ x,             // [16][2048][1024]
    const unsigned short* __restrict__ Afrag,
    float* __restrict__ s1_part,             // [NJT][NB][OUTC]
    float* __restrict__ s2_part)             // [256][OUTC]
{
    __shared__ __align__(16) unsigned short B0[4096], B1[4096]; // 8 KB each (64j x 64k)

    const int tid  = threadIdx.x;
    const int lane = tid & 63;
    const int wave = tid >> 6;
    const int blk  = blockIdx.x;   // 0..255
    const int n    = blk >> 4;
    const int jt   = blk & 15;
    const int j0   = jt * BJ;

    const float* xn = x + (size_t)n * CIN * HW;

    // B staging: thread (bj = tid&63, kh = tid>>6 in 0..7) loads 8 floats
    // (k = kh*8+i) -> one swizzled ds_write_b128.
    const int bj = tid & 63;
    const int kh = tid >> 6;
    const float* Bgp = xn + (size_t)(kh * 8) * HW + j0 + bj;
    const int offB = (kh >> 2) * 2048 + (bj >> 4) * 512 + (bj & 15) * 32
                   + ((kh & 3) ^ (bj & 3)) * 8;

    // fragment read offsets
    const int rA = lane & 15;
    const int gX = (lane >> 4) ^ (rA & 3);
    const int roffB = rA * 32 + gX * 8;            // + khalf*2048 + ni*512

    // A fragment source: wave-uniform frag base + lane*16B
    const unsigned short* Ab = Afrag + (size_t)lane * 8;

#define LDA(ks, R) { _Pragma("unroll") \
    for (int h = 0; h < 2; ++h) _Pragma("unroll") for (int t = 0; t < 2; ++t) \
        R[h * 2 + t] = *(const u32x4*)(Ab + ((((ks) * 2 + h) * 16 + 2 * wave + t) * 64) * 8); }
#define LDB(ks, F) { const float* p = Bgp + (size_t)(ks) * BK * HW; \
    _Pragma("unroll") for (int i = 0; i < 8; ++i) F[i] = p[(size_t)i * HW]; }
#define WRITEB(Bb, F) { u32x4 pk; \
    pk.x = f2bf(F[0]) | (f2bf(F[1]) << 16); pk.y = f2bf(F[2]) | (f2bf(F[3]) << 16); \
    pk.z = f2bf(F[4]) | (f2bf(F[5]) << 16); pk.w = f2bf(F[6]) | (f2bf(F[7]) << 16); \
    *(u32x4*)&Bb[offB] = pk; }
#define COMPUTE(Bb, R) { _Pragma("unroll") \
    for (int h = 0; h < 2; ++h) { \
        bf16x8 af0 = *(const bf16x8*)&R[h * 2 + 0]; \
        bf16x8 af1 = *(const bf16x8*)&R[h * 2 + 1]; \
        _Pragma("unroll") \
        for (int ni = 0; ni < 4; ++ni) { \
            bf16x8 bf = *(const bf16x8*)&Bb[h * 2048 + ni * 512 + roffB]; \
            acc[0][ni] = __builtin_amdgcn_mfma_f32_16x16x32_bf16(af0, bf, acc[0][ni], 0, 0, 0); \
            acc[1][ni] = __builtin_amdgcn_mfma_f32_16x16x32_bf16(af1, bf, acc[1][ni], 0, 0, 0); \
    } } }

    f32x4 acc[2][4] = {};
    u32x4 Aa0[4], Aa1[4];      // A reg sets: Aa0 <-> even steps (B0), Aa1 <-> odd (B1)
    float Bs0[8], Bs1[8];

    // prologue: A for steps 0,1; B for 0,1; write B0; reload Bs0 with step 2
    LDA(0, Aa0); LDB(0, Bs0);
    LDA(1, Aa1); LDB(1, Bs1);
    WRITEB(B0, Bs0);
    LDB(2, Bs0);
    block_sync_lds();

    #pragma unroll 1
    for (int ks = 0; ks < KSTEPS; ks += 2) {
        // ---- step ks (even): compute buf0 / Aa0
        COMPUTE(B0, Aa0);
        {
            int ka = (ks + 2 < KSTEPS) ? ks + 2 : KSTEPS - 1;
            LDA(ka, Aa0);                      // refill Aa0: consumed one full step later
            WRITEB(B1, Bs1);                   // stage data ks+1
            int kb = (ks + 3 < KSTEPS) ? ks + 3 : KSTEPS - 1;
            LDB(kb, Bs1);
            block_sync_lds();
        }
        // ---- step ks+1 (odd): compute buf1 / Aa1
        COMPUTE(B1, Aa1);
        {
            int ka = (ks + 3 < KSTEPS) ? ks + 3 : KSTEPS - 1;
            LDA(ka, Aa1);                      // refill Aa1: consumed one full step later
        }
        if (ks + 2 < KSTEPS) {
            WRITEB(B0, Bs0);                   // stage data ks+2
            int kb = (ks + 4 < KSTEPS) ? ks + 4 : KSTEPS - 1;
            LDB(kb, Bs0);
            block_sync_lds();
        }
    }

    // ---- epilogue: per-channel sum / sum-of-squares over this block's 64 j ----
    // C/D layout: col(j) = lane&15, row = (lane>>4)*4 + r  [m89]
    float rs[2][4], rq[2][4];
    #pragma unroll
    for (int mi = 0; mi < 2; ++mi) {
        #pragma unroll
        for (int r = 0; r < 4; ++r) {
            float s = 0.f, q = 0.f;
            #pragma unroll
            for (int ni = 0; ni < 4; ++ni) {
                float v = acc[mi][ni][r];
                s += v; q += v * v;
            }
            rs[mi][r] = s; rq[mi][r] = q;
        }
    }
    #pragma unroll
    for (int m = 1; m < 16; m <<= 1) {
        #pragma unroll
        for (int mi = 0; mi < 2; ++mi) {
            #pragma unroll
            for (int r = 0; r < 4; ++r) {
                rs[mi][r] += __shfl_xor(rs[mi][r], m, 64);
                rq[mi][r] += __shfl_xor(rq[mi][r], m, 64);
            }
        }
    }
    if (rA == 0) {
        const int gK = lane >> 4;
        #pragma unroll
        for (int mi = 0; mi < 2; ++mi) {
            #pragma unroll
            for (int r = 0; r < 4; ++r) {
                int o = wave * 32 + mi * 16 + gK * 4 + r;
                s1_part[(jt * NB + n) * OUTC + o] = rs[mi][r];
                s2_part[blk * OUTC + o]           = rq[mi][r];
            }
        }
    }
#undef LDA
#undef LDB
#undef WRITEB
#undef COMPUTE
}

// ---- kernel 3 (fused finalize+broadcast): block = (n, 16 channels).
__global__ __launch_bounds__(256) void finalize_bcast_kernel(
    const float* __restrict__ s1_part,   // [NJT][NB][OUTC]
    const float* __restrict__ s2_part,   // [256][OUTC]
    const float* __restrict__ gamma,
    const float* __restrict__ beta,
    float* __restrict__ out)             // [NB][OUTC][1024]
{
    const int tid   = threadIdx.x;
    const int slice = tid & 15;
    const int o_l   = tid >> 4;
    const int n0    = blockIdx.x >> 4;
    const int o     = (blockIdx.x & 15) * 16 + o_l;

    float S1 = 0.f, S2 = 0.f;
    #pragma unroll
    for (int q = 0; q < 16; ++q) {
        int p = slice * 16 + q;          // covers all 256 partials
        S1 += s1_part[p * OUTC + o];
        S2 += s2_part[p * OUTC + o];
    }
    float s1n = s1_part[(slice * NB + n0) * OUTC + o];   // jt = slice
    #pragma unroll
    for (int m = 1; m < 16; m <<= 1) {
        S1  += __shfl_xor(S1, m, 64);
        S2  += __shfl_xor(S2, m, 64);
        s1n += __shfl_xor(s1n, m, 64);
    }
    float mean = S1 * (1.f / 16384.f);
    float var  = S2 * (1.f / 16384.f) - mean * mean;   // biased var (matches ref)
    float inv  = rsqrtf(var + 1e-5f);
    float v = gamma[o] * (s1n * (1.f / 1024.f) - mean) * inv + beta[o];

    float4 vv = make_float4(v, v, v, v);
    float4* dst = reinterpret_cast<float4*>(out + ((size_t)(n0 * OUTC + o)) * HW);
    #pragma unroll
    for (int it = 0; it < 16; ++it)
        dst[it * 16 + slice] = vv;
}

extern "C" void kernel_launch(void* const* d_in, const int* in_sizes, int n_in,
                              void* d_out, int out_size, void* d_ws, size_t ws_size,
                              hipStream_t stream) {
    const float* x     = (const float*)d_in[0];
    const float* W     = (const float*)d_in[1];
    const float* gamma = (const float*)d_in[2];
    const float* beta  = (const float*)d_in[3];
    float* out = (float*)d_out;

    char* ws = (char*)d_ws;
    unsigned short* Afrag = (unsigned short*)ws;                 // 1 MiB
    float* s1_part = (float*)(ws + (1 << 20));                   // 256 KB
    float* s2_part = (float*)(ws + (1 << 20) + (256 << 10));     // 256 KB

    hipLaunchKernelGGL(wprep_kernel, dim3(256), dim3(256), 0, stream, W, Afrag);
    hipLaunchKernelGGL(gemm_stats_kernel, dim3(256), dim3(512), 0, stream,
                       x, Afrag, s1_part, s2_part);
    hipLaunchKernelGGL(finalize_bcast_kernel, dim3(NB * (OUTC / 16)), dim3(256), 0, stream,
                       s1_part, s2_part, gamma, beta, out);
}

// Round 7
// 48.029 us; speedup vs baseline: 1.1579x; 1.0080x over previous
//
#include <hip/hip_runtime.h>
#include <hip/hip_bf16.h>
#include <stdint.h>

#define NB   16
#define CIN  2048
#define OUTC 256
#define HW   1024
#define BJ   64
#define BK   64
#define NJT  (HW / BJ)          // 16 j-tiles
#define KSTEPS (CIN / BK)       // 32 steps of 64 k

typedef __attribute__((ext_vector_type(8))) short bf16x8;
typedef __attribute__((ext_vector_type(4))) float f32x4;
typedef __attribute__((ext_vector_type(4))) unsigned int u32x4;

__device__ __forceinline__ unsigned int f2bf(float f) {
    union { float f; unsigned int u; } a; a.f = f;
    return (a.u + 0x7FFFu + ((a.u >> 16) & 1u)) >> 16;  // RNE
}

// Raw barrier: drains LDS ops only; global prefetch loads stay in flight.
__device__ __forceinline__ void block_sync_lds() {
    asm volatile("s_waitcnt lgkmcnt(0)" ::: "memory");
    __builtin_amdgcn_s_barrier();
    asm volatile("" ::: "memory");
}

// ---- kernel 1: W fp32 -> bf16 A-fragments in MFMA lane order.
//      Afrag[ks32][ot][lane][8 bf16]: lane l of fragment (ks32, ot) holds
//      A[row = ot*16 + (l&15)][k = ks32*32 + (l>>4)*8 + i]  (m89 layout).
__global__ void wprep_kernel(const float* __restrict__ W, unsigned short* __restrict__ Afrag) {
    int g  = blockIdx.x * blockDim.x + threadIdx.x;   // 65536
    int o  = g >> 8;           // 0..255
    int kc = g & 255;          // 8-k chunk within row
    const float4* p = reinterpret_cast<const float4*>(W + o * CIN + kc * 8);
    float4 v0 = p[0], v1 = p[1];
    u32x4 pk;
    pk.x = f2bf(v0.x) | (f2bf(v0.y) << 16);
    pk.y = f2bf(v0.z) | (f2bf(v0.w) << 16);
    pk.z = f2bf(v1.x) | (f2bf(v1.y) << 16);
    pk.w = f2bf(v1.z) | (f2bf(v1.w) << 16);
    int ks32 = kc >> 2, g8 = kc & 3;
    int lane = g8 * 16 + (o & 15), ot = o >> 4;
    *reinterpret_cast<u32x4*>(Afrag + (((size_t)ks32 * 16 + ot) * 64 + lane) * 8) = pk;
}

// ---- kernel 2: per-batch GEMM, B-only LDS in FRAGMENT-LINEAR (MFMA lane
//      order) layout: lane l of fragment (h, ni) reads bytes [l*16, l*16+16)
//      of a contiguous 1 KB region -> zero bank conflicts on read AND write.
__global__ __launch_bounds__(512, 2) void gemm_stats_kernel(
    const float* __restrict__ x,             // [16][2048][1024]
    const unsigned short* __restrict__ Afrag,
    float* __restrict__ s1_part,             // [NJT][NB][OUTC]
    float* __restrict__ s2_part)             // [256][OUTC]
{
    __shared__ __align__(16) unsigned short B0[4096], B1[4096]; // 8 KB each (64j x 64k)

    const int tid  = threadIdx.x;
    const int lane = tid & 63;
    const int wave = tid >> 6;
    const int blk  = blockIdx.x;   // 0..255
    const int n    = blk >> 4;
    const int jt   = blk & 15;
    const int j0   = jt * BJ;

    const float* xn = x + (size_t)n * CIN * HW;

    // B staging: thread (bj = tid&63, kh = tid>>6 in 0..7) loads 8 floats
    // (k = kh*8+i) -> one ds_write_b128 at its fragment-linear slot:
    // region (h = kh>>2, ni = bj>>4), slot (g = kh&3, j = bj&15).
    const int bj = tid & 63;
    const int kh = tid >> 6;
    const float* Bgp = xn + (size_t)(kh * 8) * HW + j0 + bj;
    const int offB = (kh >> 2) * 2048 + (bj >> 4) * 512 + (kh & 3) * 128 + (bj & 15) * 8;

    // fragment read base (shorts): lane-linear within each (h, ni) 1 KB region
    const int rbase = lane * 8;                    // + h*2048 + ni*512

    // A fragment source: wave-uniform frag base + lane*16B
    const unsigned short* Ab = Afrag + (size_t)lane * 8;

#define LDA(ks, R) { _Pragma("unroll") \
    for (int h = 0; h < 2; ++h) _Pragma("unroll") for (int t = 0; t < 2; ++t) \
        R[h * 2 + t] = *(const u32x4*)(Ab + ((((ks) * 2 + h) * 16 + 2 * wave + t) * 64) * 8); }
#define LDB(ks, F) { const float* p = Bgp + (size_t)(ks) * BK * HW; \
    _Pragma("unroll") for (int i = 0; i < 8; ++i) F[i] = p[(size_t)i * HW]; }
#define WRITEB(Bb, F) { u32x4 pk; \
    pk.x = f2bf(F[0]) | (f2bf(F[1]) << 16); pk.y = f2bf(F[2]) | (f2bf(F[3]) << 16); \
    pk.z = f2bf(F[4]) | (f2bf(F[5]) << 16); pk.w = f2bf(F[6]) | (f2bf(F[7]) << 16); \
    *(u32x4*)&Bb[offB] = pk; }
#define COMPUTE(Bb, R) { _Pragma("unroll") \
    for (int h = 0; h < 2; ++h) { \
        bf16x8 af0 = *(const bf16x8*)&R[h * 2 + 0]; \
        bf16x8 af1 = *(const bf16x8*)&R[h * 2 + 1]; \
        _Pragma("unroll") \
        for (int ni = 0; ni < 4; ++ni) { \
            bf16x8 bf = *(const bf16x8*)&Bb[h * 2048 + ni * 512 + rbase]; \
            acc[0][ni] = __builtin_amdgcn_mfma_f32_16x16x32_bf16(af0, bf, acc[0][ni], 0, 0, 0); \
            acc[1][ni] = __builtin_amdgcn_mfma_f32_16x16x32_bf16(af1, bf, acc[1][ni], 0, 0, 0); \
    } } }

    f32x4 acc[2][4] = {};
    u32x4 Aa0[4], Aa1[4];      // A reg sets: Aa0 <-> even steps (B0), Aa1 <-> odd (B1)
    float Bs0[8], Bs1[8];

    // prologue: A for steps 0,1; B for 0,1; write B0; reload Bs0 with step 2
    LDA(0, Aa0); LDB(0, Bs0);
    LDA(1, Aa1); LDB(1, Bs1);
    WRITEB(B0, Bs0);
    LDB(2, Bs0);
    block_sync_lds();

    #pragma unroll 1
    for (int ks = 0; ks < KSTEPS; ks += 2) {
        // ---- step ks (even): compute buf0 / Aa0
        COMPUTE(B0, Aa0);
        {
            int ka = (ks + 2 < KSTEPS) ? ks + 2 : KSTEPS - 1;
            LDA(ka, Aa0);                      // refill Aa0: consumed one full step later
            WRITEB(B1, Bs1);                   // stage data ks+1
            int kb = (ks + 3 < KSTEPS) ? ks + 3 : KSTEPS - 1;
            LDB(kb, Bs1);
            block_sync_lds();
        }
        // ---- step ks+1 (odd): compute buf1 / Aa1
        COMPUTE(B1, Aa1);
        {
            int ka = (ks + 3 < KSTEPS) ? ks + 3 : KSTEPS - 1;
            LDA(ka, Aa1);                      // refill Aa1: consumed one full step later
        }
        if (ks + 2 < KSTEPS) {
            WRITEB(B0, Bs0);                   // stage data ks+2
            int kb = (ks + 4 < KSTEPS) ? ks + 4 : KSTEPS - 1;
            LDB(kb, Bs0);
            block_sync_lds();
        }
    }

    // ---- epilogue: per-channel sum / sum-of-squares over this block's 64 j ----
    // C/D layout: col(j) = lane&15, row = (lane>>4)*4 + r  [m89]
    float rs[2][4], rq[2][4];
    #pragma unroll
    for (int mi = 0; mi < 2; ++mi) {
        #pragma unroll
        for (int r = 0; r < 4; ++r) {
            float s = 0.f, q = 0.f;
            #pragma unroll
            for (int ni = 0; ni < 4; ++ni) {
                float v = acc[mi][ni][r];
                s += v; q += v * v;
            }
            rs[mi][r] = s; rq[mi][r] = q;
        }
    }
    #pragma unroll
    for (int m = 1; m < 16; m <<= 1) {
        #pragma unroll
        for (int mi = 0; mi < 2; ++mi) {
            #pragma unroll
            for (int r = 0; r < 4; ++r) {
                rs[mi][r] += __shfl_xor(rs[mi][r], m, 64);
                rq[mi][r] += __shfl_xor(rq[mi][r], m, 64);
            }
        }
    }
    const int rA = lane & 15;
    if (rA == 0) {
        const int gK = lane >> 4;
        #pragma unroll
        for (int mi = 0; mi < 2; ++mi) {
            #pragma unroll
            for (int r = 0; r < 4; ++r) {
                int o = wave * 32 + mi * 16 + gK * 4 + r;
                s1_part[(jt * NB + n) * OUTC + o] = rs[mi][r];
                s2_part[blk * OUTC + o]           = rq[mi][r];
            }
        }
    }
#undef LDA
#undef LDB
#undef WRITEB
#undef COMPUTE
}

// ---- kernel 3 (fused finalize+broadcast): block = (n, 16 channels).
__global__ __launch_bounds__(256) void finalize_bcast_kernel(
    const float* __restrict__ s1_part,   // [NJT][NB][OUTC]
    const float* __restrict__ s2_part,   // [256][OUTC]
    const float* __restrict__ gamma,
    const float* __restrict__ beta,
    float* __restrict__ out)             // [NB][OUTC][1024]
{
    const int tid   = threadIdx.x;
    const int slice = tid & 15;
    const int o_l   = tid >> 4;
    const int n0    = blockIdx.x >> 4;
    const int o     = (blockIdx.x & 15) * 16 + o_l;

    float S1 = 0.f, S2 = 0.f;
    #pragma unroll
    for (int q = 0; q < 16; ++q) {
        int p = slice * 16 + q;          // covers all 256 partials
        S1 += s1_part[p * OUTC + o];
        S2 += s2_part[p * OUTC + o];
    }
    float s1n = s1_part[(slice * NB + n0) * OUTC + o];   // jt = slice
    #pragma unroll
    for (int m = 1; m < 16; m <<= 1) {
        S1  += __shfl_xor(S1, m, 64);
        S2  += __shfl_xor(S2, m, 64);
        s1n += __shfl_xor(s1n, m, 64);
    }
    float mean = S1 * (1.f / 16384.f);
    float var  = S2 * (1.f / 16384.f) - mean * mean;   // biased var (matches ref)
    float inv  = rsqrtf(var + 1e-5f);
    float v = gamma[o] * (s1n * (1.f / 1024.f) - mean) * inv + beta[o];

    float4 vv = make_float4(v, v, v, v);
    float4* dst = reinterpret_cast<float4*>(out + ((size_t)(n0 * OUTC + o)) * HW);
    #pragma unroll
    for (int it = 0; it < 16; ++it)
        dst[it * 16 + slice] = vv;
}

extern "C" void kernel_launch(void* const* d_in, const int* in_sizes, int n_in,
                              void* d_out, int out_size, void* d_ws, size_t ws_size,
                              hipStream_t stream) {
    const float* x     = (const float*)d_in[0];
    const float* W     = (const float*)d_in[1];
    const float* gamma = (const float*)d_in[2];
    const float* beta  = (const float*)d_in[3];
    float* out = (float*)d_out;

    char* ws = (char*)d_ws;
    unsigned short* Afrag = (unsigned short*)ws;                 // 1 MiB
    float* s1_part = (float*)(ws + (1 << 20));                   // 256 KB
    float* s2_part = (float*)(ws + (1 << 20) + (256 << 10));     // 256 KB

    hipLaunchKernelGGL(wprep_kernel, dim3(256), dim3(256), 0, stream, W, Afrag);
    hipLaunchKernelGGL(gemm_stats_kernel, dim3(256), dim3(512), 0, stream,
                       x, Afrag, s1_part, s2_part);
    hipLaunchKernelGGL(finalize_bcast_kernel, dim3(NB * (OUTC / 16)), dim3(256), 0, stream,
                       s1_part, s2_part, gamma, beta, out);
}